// Round 2
// baseline (451.584 us; speedup 1.0000x reference)
//
#include <hip/hip_runtime.h>
#include <cstdint>
#include <cstddef>

#define Bv 8
#define Av 16384
#define Sv 2048
#define Dv 512
#define OUTv 512
#define Mv (Bv * Sv)
#define SP1 (Sv + 1)

using u16 = unsigned short;
using f32x4 = __attribute__((ext_vector_type(4))) float;
using bf16x8 = __attribute__((ext_vector_type(8))) short;

__device__ __forceinline__ u16 f2bf(float x) {
  union { float f; uint32_t u; } v; v.f = x;
  uint32_t u = v.u;
  uint32_t r = u + 0x7FFFu + ((u >> 16) & 1u);   // round-to-nearest-even
  return (u16)(r >> 16);
}
__device__ __forceinline__ float bf2f(u16 h) {
  union { uint32_t u; float f; } v; v.u = ((uint32_t)h) << 16; return v.f;
}
__device__ __forceinline__ int clamp_len(int x, int hi) {
  return x < 0 ? 0 : (x > hi ? hi : x);
}

// ---------------------------------------------------------------------------
// Kernel 1 (init): fused
//  a) starts[b][s] = lower_bound(ids_b, s) for s in [0, Sv] — scatter from the
//     sorted ids array, one thread per atom (no per-block binary search later)
//  b) W fp32 -> bf16
//  c) zero avg_sum / n_fill (replaces hipMemsetAsync)
// grid: 512 starts-blocks + 256 wconv-blocks, 256 threads.
// ---------------------------------------------------------------------------
#define NBLK_STARTS ((Bv * Av) / 256)
#define NBLK_WCONV  ((OUTv * Dv) / (256 * 4))

__global__ __launch_bounds__(256)
void init_kernel(const int* __restrict__ res_ids, const int* __restrict__ aa_len,
                 const float* __restrict__ W, int* __restrict__ starts,
                 u16* __restrict__ Wb, float* __restrict__ avg_sum,
                 int* __restrict__ n_fill) {
  const int blk = blockIdx.x;
  const int t = threadIdx.x;
  if (blk < NBLK_STARTS) {
    const int gid = blk * 256 + t;
    if (gid < Bv * Dv) avg_sum[gid] = 0.0f;
    if (gid < Bv) n_fill[gid] = 0;
    const int b = gid >> 14;           // / Av
    const int a = gid & (Av - 1);
    const int alen = clamp_len(aa_len[b], Av);
    const int* ids = res_ids + b * Av;
    int* st = starts + b * SP1;
    if (alen == 0) {
      if (a == 0) for (int s = 0; s <= Sv; ++s) st[s] = 0;
      return;
    }
    if (a >= alen) return;
    int cur = ids[a];  cur = cur < 0 ? 0 : (cur > Sv - 1 ? Sv - 1 : cur);
    int prev = (a == 0) ? -1 : ids[a - 1];
    prev = prev < -1 ? -1 : (prev > Sv - 1 ? Sv - 1 : prev);
    for (int s = prev + 1; s <= cur; ++s) st[s] = a;
    if (a == alen - 1) for (int s = cur + 1; s <= Sv; ++s) st[s] = alen;
  } else {
    const int i = ((blk - NBLK_STARTS) * 256 + t) * 4;
    float4 v = *(const float4*)(W + i);
    ushort4 o = { f2bf(v.x), f2bf(v.y), f2bf(v.z), f2bf(v.w) };
    *(ushort4*)(Wb + i) = o;
  }
}

// ---------------------------------------------------------------------------
// Kernel 2 (pool): block (b,s) reads its contiguous atom range [start,end)
// from the starts table; 128 threads x float4 cols, 2-way unrolled.
// Rows with s >= seq_len are zeroed here (reference masks them to 0).
// ---------------------------------------------------------------------------
__global__ __launch_bounds__(128)
void pool_kernel(const float* __restrict__ rep, const int* __restrict__ starts,
                 const int* __restrict__ seq_len, u16* __restrict__ pooled) {
  const int bs = blockIdx.x;
  const int b = bs >> 11;              // / Sv
  const int s = bs & (Sv - 1);
  const int t = threadIdx.x;           // cols 4t..4t+3
  u16* orow = pooled + (size_t)bs * Dv + t * 4;
  const int slen = clamp_len(seq_len[b], Sv);
  if (s >= slen) {
    ushort4 z = {0, 0, 0, 0};
    *(ushort4*)orow = z;
    return;
  }
  const int start = starts[b * SP1 + s];
  const int end   = starts[b * SP1 + s + 1];
  const int cnt = end - start;

  f32x4 acc = (f32x4){0.f, 0.f, 0.f, 0.f};
  const float* base = rep + (size_t)b * Av * Dv + t * 4;
  int a = start;
  for (; a + 2 <= end; a += 2) {
    f32x4 v0 = *(const f32x4*)(base + (size_t)a * Dv);
    f32x4 v1 = *(const f32x4*)(base + (size_t)(a + 1) * Dv);
    acc += v0; acc += v1;
  }
  if (a < end) acc += *(const f32x4*)(base + (size_t)a * Dv);

  const float inv = cnt > 0 ? 1.0f / (float)cnt : 0.0f;
  ushort4 o = { f2bf(acc[0] * inv), f2bf(acc[1] * inv),
                f2bf(acc[2] * inv), f2bf(acc[3] * inv) };
  *(ushort4*)orow = o;
}

// ---------------------------------------------------------------------------
// Kernel 3 (avg): per-batch sum of filled pooled rows. grid (Bv, 16) x 256.
// Fill flags staged through LDS (one coalesced pass) to kill the per-iter
// global-latency chain. Thread t covers cols 2t, 2t+1.
// ---------------------------------------------------------------------------
__global__ __launch_bounds__(256)
void avg_kernel(const u16* __restrict__ pooled, const int* __restrict__ starts,
                const int* __restrict__ seq_len, float* __restrict__ avg_sum,
                int* __restrict__ n_fill) {
  __shared__ int flag[128];
  const int b = blockIdx.x;
  const int chunk = blockIdx.y;        // 0..15
  const int t = threadIdx.x;           // 0..255
  const int slen = clamp_len(seq_len[b], Sv);
  const int s0 = chunk * 128;
  if (t < 128) {
    const int s = s0 + t;
    const int st0 = starts[b * SP1 + s];
    const int st1 = starts[b * SP1 + s + 1];
    flag[t] = (s < slen && st1 > st0) ? 1 : 0;
  }
  __syncthreads();
  float a0 = 0.f, a1 = 0.f;
  const u16* prow = pooled + ((size_t)(b * Sv + s0)) * Dv + t * 2;
  for (int i = 0; i < 128; ++i) {
    if (flag[i]) {
      uint32_t v = *(const uint32_t*)(prow + (size_t)i * Dv);
      a0 += bf2f((u16)(v & 0xffff));
      a1 += bf2f((u16)(v >> 16));
    }
  }
  atomicAdd(&avg_sum[b * Dv + t * 2 + 0], a0);
  atomicAdd(&avg_sum[b * Dv + t * 2 + 1], a1);
  if (t == 0) {
    int c = 0;
    for (int i = 0; i < 128; ++i) c += flag[i];
    atomicAdd(&n_fill[b], c);
  }
}

// ---------------------------------------------------------------------------
// Kernel 4 (fixup): one thread per residue; empty in-range rows (rare, ~1 per
// batch) get the per-batch filled average. grid (Bv, Sv/256) x 256.
// ---------------------------------------------------------------------------
__global__ __launch_bounds__(256)
void fixup_kernel(u16* __restrict__ pooled, const int* __restrict__ starts,
                  const int* __restrict__ seq_len, const float* __restrict__ avg_sum,
                  const int* __restrict__ n_fill) {
  const int b = blockIdx.x;
  const int s = blockIdx.y * 256 + threadIdx.x;
  const int slen = clamp_len(seq_len[b], Sv);
  if (s >= slen) return;                      // already zeroed by pool
  const int st0 = starts[b * SP1 + s];
  const int st1 = starts[b * SP1 + s + 1];
  if (st1 > st0) return;                      // filled — nothing to do
  const int nf = n_fill[b];
  const float inv = 1.0f / (float)(nf > 0 ? nf : 1);
  u16* orow = pooled + (size_t)(b * Sv + s) * Dv;
  const float* arow = avg_sum + b * Dv;
  for (int c = 0; c < Dv; c += 4) {
    f32x4 v = *(const f32x4*)(arow + c);
    ushort4 o = { f2bf(v[0] * inv), f2bf(v[1] * inv),
                  f2bf(v[2] * inv), f2bf(v[3] * inv) };
    *(ushort4*)(orow + c) = o;
  }
}

// ---------------------------------------------------------------------------
// Kernel 5 (GEMM): out[m,n] = sum_k pooled[m,k] * W[n,k] + bias[n] (bf16 MFMA)
// 128x128 block tile, 4 waves of 64x64 (4x4 of 16x16x32), BK=32, LDS pad to 40.
// ---------------------------------------------------------------------------
#define BM 128
#define BN 128
#define BK 32
#define LDT 40

__global__ __launch_bounds__(256, 2)
void gemm_kernel(const u16* __restrict__ A, const u16* __restrict__ Bw,
                 const float* __restrict__ bias, float* __restrict__ out) {
  __shared__ u16 As[BM * LDT];
  __shared__ u16 Bs[BN * LDT];
  const int tid = threadIdx.x;
  const int m0 = blockIdx.x * BM;
  const int n0 = blockIdx.y * BN;
  const int lane = tid & 63;
  const int wave = tid >> 6;
  const int wm = (wave & 1) * 64;
  const int wn = (wave >> 1) * 64;
  const int fr = lane & 15;
  const int fq = lane >> 4;

  f32x4 acc[4][4];
#pragma unroll
  for (int i = 0; i < 4; ++i)
#pragma unroll
    for (int j = 0; j < 4; ++j) acc[i][j] = (f32x4){0.f, 0.f, 0.f, 0.f};

  const int r0 = tid >> 2, kc0 = (tid & 3) * 8;
  const int r1 = (tid + 256) >> 2, kc1 = ((tid + 256) & 3) * 8;

  for (int k0 = 0; k0 < Dv; k0 += BK) {
    __syncthreads();
    *(bf16x8*)(As + r0 * LDT + kc0) = *(const bf16x8*)(A + (size_t)(m0 + r0) * Dv + k0 + kc0);
    *(bf16x8*)(As + r1 * LDT + kc1) = *(const bf16x8*)(A + (size_t)(m0 + r1) * Dv + k0 + kc1);
    *(bf16x8*)(Bs + r0 * LDT + kc0) = *(const bf16x8*)(Bw + (size_t)(n0 + r0) * Dv + k0 + kc0);
    *(bf16x8*)(Bs + r1 * LDT + kc1) = *(const bf16x8*)(Bw + (size_t)(n0 + r1) * Dv + k0 + kc1);
    __syncthreads();

    bf16x8 af[4], bfr[4];
#pragma unroll
    for (int mi = 0; mi < 4; ++mi)
      af[mi] = *(const bf16x8*)(As + (wm + mi * 16 + fr) * LDT + fq * 8);
#pragma unroll
    for (int ni = 0; ni < 4; ++ni)
      bfr[ni] = *(const bf16x8*)(Bs + (wn + ni * 16 + fr) * LDT + fq * 8);
#pragma unroll
    for (int mi = 0; mi < 4; ++mi)
#pragma unroll
      for (int ni = 0; ni < 4; ++ni)
        acc[mi][ni] = __builtin_amdgcn_mfma_f32_16x16x32_bf16(af[mi], bfr[ni], acc[mi][ni], 0, 0, 0);
  }

#pragma unroll
  for (int mi = 0; mi < 4; ++mi) {
#pragma unroll
    for (int ni = 0; ni < 4; ++ni) {
      const int col = n0 + wn + ni * 16 + fr;
      const float bv = bias[col];
#pragma unroll
      for (int r = 0; r < 4; ++r) {
        const int row = m0 + wm + mi * 16 + fq * 4 + r;
        out[(size_t)row * OUTv + col] = acc[mi][ni][r] + bv;
      }
    }
  }
}

// ---------------------------------------------------------------------------
// Workspace layout (bytes):
//   [0,        16777216)  pooled bf16 [M, D]
//   [16777216, 17301504)  Wb bf16 [OUT, D]
//   [17301504, 17367072)  starts int [B, Sv+1]
//   [17367072, 17383456)  avg_sum float [B, D]
//   [17383456, 17383488)  n_fill int [B]
// ---------------------------------------------------------------------------
extern "C" void kernel_launch(void* const* d_in, const int* in_sizes, int n_in,
                              void* d_out, int out_size, void* d_ws, size_t ws_size,
                              hipStream_t stream) {
  (void)in_sizes; (void)n_in; (void)out_size; (void)ws_size;
  const float* rep     = (const float*)d_in[0];
  const int*   res_ids = (const int*)d_in[1];
  const int*   aa_len  = (const int*)d_in[2];
  const int*   seq_len = (const int*)d_in[3];
  const float* W       = (const float*)d_in[4];
  const float* bias    = (const float*)d_in[5];
  float* out = (float*)d_out;

  char* ws = (char*)d_ws;
  u16*   pooled  = (u16*)ws;
  u16*   Wb      = (u16*)(ws + 16777216);
  int*   starts  = (int*)(ws + 17301504);
  float* avg_sum = (float*)(ws + 17367072);
  int*   n_fill  = (int*)(ws + 17383456);

  init_kernel<<<NBLK_STARTS + NBLK_WCONV, 256, 0, stream>>>(
      res_ids, aa_len, W, starts, Wb, avg_sum, n_fill);
  pool_kernel<<<Mv, 128, 0, stream>>>(rep, starts, seq_len, pooled);
  avg_kernel<<<dim3(Bv, 16), 256, 0, stream>>>(pooled, starts, seq_len, avg_sum, n_fill);
  fixup_kernel<<<dim3(Bv, Sv / 256), 256, 0, stream>>>(pooled, starts, seq_len, avg_sum, n_fill);
  gemm_kernel<<<dim3(Mv / BM, OUTv / BN), 256, 0, stream>>>(pooled, Wb, bias, out);
}